// Round 18
// baseline (229.383 us; speedup 1.0000x reference)
//
#include <hip/hip_runtime.h>

// Decoder block: B=2 T=2048 D=1024 H=16 hd=64 HIDDEN=4096. All f32 in/out,
// bf16 MFMA internally (threshold is bf16-floor).

typedef __bf16 bf16_t;
typedef bf16_t bf16x8 __attribute__((ext_vector_type(8)));
typedef float f32x4 __attribute__((ext_vector_type(4)));

#define M_ROWS 4096   // B*T
#define DMODEL 1024
#define TSEQ   2048
#define NHEAD  16
#define HDIM   64

__device__ __forceinline__ ushort f2bf(float f) {
  union { float f; unsigned u; } v; v.f = f;
  unsigned r = (v.u + 0x7fffu + ((v.u >> 16) & 1u)) >> 16;
  return (ushort)r;
}
__device__ __forceinline__ float bf2f(ushort u) {
  union { unsigned u; float f; } v; v.u = ((unsigned)u) << 16;
  return v.f;
}
__device__ __forceinline__ unsigned cvt_pk_bf16(float a, float b) {
  unsigned r;
  asm("v_cvt_pk_bf16_f32 %0, %1, %2" : "=v"(r) : "v"(a), "v"(b));
  return r;
}
__device__ __forceinline__ void gload_lds16(const void* g, void* l) {
  __builtin_amdgcn_global_load_lds(
      (const __attribute__((address_space(1))) unsigned*)g,
      (__attribute__((address_space(3))) unsigned*)l, 16, 0, 0);
}
__device__ __forceinline__ f32x4 mfma16(bf16x8 a, bf16x8 b, f32x4 c) {
  return __builtin_amdgcn_mfma_f32_16x16x32_bf16(a, b, c, 0, 0, 0);
}
__device__ __forceinline__ float gelu_f(float x) {
  float y = 0.7978845608028654f * (x + 0.044715f * x * x * x);
  float e = __expf(2.0f * y);
  float t = 1.0f - 2.0f / (e + 1.0f);   // tanh(y), overflow-safe
  return 0.5f * x * (1.0f + t);
}

// ---------------- batched weight transpose + f32->bf16 ---------------------
__global__ __launch_bounds__(256)
void transpose_all(const float* __restrict__ wqkv, const float* __restrict__ wo,
                   const float* __restrict__ w1, const float* __restrict__ w2,
                   ushort* __restrict__ dqkv, ushort* __restrict__ dwo,
                   ushort* __restrict__ dw1, ushort* __restrict__ dw2) {
  int id = blockIdx.x;
  const float* src; ushort* dst; int K, N, nx, loc;
  if (id < 3072)      { src = wqkv; dst = dqkv; K = 1024; N = 3072; nx = 96;  loc = id; }
  else if (id < 4096) { src = wo;   dst = dwo;  K = 1024; N = 1024; nx = 32;  loc = id - 3072; }
  else if (id < 8192) { src = w1;   dst = dw1;  K = 1024; N = 4096; nx = 128; loc = id - 4096; }
  else                { src = w2;   dst = dw2;  K = 4096; N = 1024; nx = 32;  loc = id - 8192; }
  int n0 = (loc % nx) * 32, k0 = (loc / nx) * 32;
  __shared__ float t[32][33];
  int tx = threadIdx.x & 31, ty = threadIdx.x >> 5;
#pragma unroll
  for (int i = 0; i < 4; i++) {
    int k = ty + i * 8;
    t[k][tx] = src[(size_t)(k0 + k) * N + n0 + tx];
  }
  __syncthreads();
#pragma unroll
  for (int i = 0; i < 4; i++) {
    int nn = ty + i * 8;
    dst[(size_t)(n0 + nn) * K + k0 + tx] = f2bf(t[tx][nn]);
  }
}

// ---------------- layernorm (f32 in, bf16 out) -----------------------------
__global__ __launch_bounds__(256)
void ln_kernel(const float* __restrict__ x, const float* __restrict__ sc,
               const float* __restrict__ bi, ushort* __restrict__ out) {
  int row = blockIdx.x;
  int tid = threadIdx.x;
  const float4 v = *(const float4*)&x[(size_t)row * DMODEL + tid * 4];
  float s = v.x + v.y + v.z + v.w;
  float s2 = v.x * v.x + v.y * v.y + v.z * v.z + v.w * v.w;
#pragma unroll
  for (int off = 32; off > 0; off >>= 1) {
    s += __shfl_down(s, off);
    s2 += __shfl_down(s2, off);
  }
  __shared__ float red[8];
  int lane = tid & 63, w = tid >> 6;
  if (lane == 0) { red[w * 2] = s; red[w * 2 + 1] = s2; }
  __syncthreads();
  float S = red[0] + red[2] + red[4] + red[6];
  float S2 = red[1] + red[3] + red[5] + red[7];
  float mu = S * (1.0f / DMODEL);
  float var = S2 * (1.0f / DMODEL) - mu * mu;
  float rs = rsqrtf(var + 1e-6f);
  float4 scv = *(const float4*)&sc[tid * 4];
  float4 biv = *(const float4*)&bi[tid * 4];
  ushort4 o;
  o.x = f2bf((v.x - mu) * rs * scv.x + biv.x);
  o.y = f2bf((v.y - mu) * rs * scv.y + biv.y);
  o.z = f2bf((v.z - mu) * rs * scv.z + biv.z);
  o.w = f2bf((v.w - mu) * rs * scv.w + biv.w);
  *(ushort4*)&out[(size_t)row * DMODEL + tid * 4] = o;
}

// ---------------- rope table -----------------------------------------------
__global__ __launch_bounds__(256)
void rope_table(const int* __restrict__ positions, float2* __restrict__ tab) {
  int i = blockIdx.x * 256 + threadIdx.x;  // T*32
  int t = i >> 5, f = i & 31;
  float inv = __expf(-(float)f * (1.0f / 32.0f) * 9.210340371976184f);
  float a = (float)positions[t] * inv;
  tab[i] = make_float2(cosf(a), sinf(a));
}

// ---------------- ring-3 counted-vmcnt GEMM core macro helpers -------------
// LDS: lA[3][128*64] (48KB) | lB[3][64*64] (24KB) = 72KB dynamic -> 2 blk/CU.
// Loop t: vmcnt(6)+barrier (tile t's 6 loads were issued at t-2, ~2 full
// MFMA phases earlier -> wait is ~free; FIFO vmcnt keeps t+1's 6 in flight;
// NEVER drains in steady state) -> issue stage(t+2) -> ds_read -> 16 MFMA.

// ---------------- fused QKV GEMM + RoPE + reshape --------------------------
// BM=128, BN=64 (one head/block), ring-3 pipeline. Epilogue: acc -> LDS f32
// tile -> bn<16: Q (RoPE, pre-scaled 0.125*log2e); bn<32: K (RoPE); else V^T.
__global__ __launch_bounds__(256)
void qkv_gemm(const ushort* __restrict__ A, const ushort* __restrict__ Bt,
              const float2* __restrict__ tab, ushort* __restrict__ Qo,
              ushort* __restrict__ Ko, ushort* __restrict__ VTo, int K,
              int nbn) {
  extern __shared__ ushort smem[];
  ushort* lA = smem;             // [3][8192]
  ushort* lB = smem + 24576;     // [3][4096]
  int tid = threadIdx.x;
  int lane = tid & 63, w = tid >> 6;
  int wm = w >> 1, wn = w & 1;

  int nwg = gridDim.x;
  int cpx = nwg >> 3;
  int wg = ((int)blockIdx.x & 7) * cpx + ((int)blockIdx.x >> 3);
  int bm = wg / nbn, bn = wg % nbn;

  f32x4 acc[4][2] = {};

  const ushort* Ab = A + (size_t)bm * 128 * K;
  const ushort* Bb = Bt + (size_t)bn * 64 * K;
  int lrow = lane & 15, lg = lane >> 4;
  int srow = tid >> 3, sch = tid & 7;

  auto stage = [&](int buf, int k0) {
#pragma unroll
    for (int c = 0; c < 4; c++) {
      int r = c * 32 + srow;
      int gch = sch ^ (r & 7);
      gload_lds16(Ab + (size_t)r * K + k0 + gch * 8,
                  &lA[buf * 8192 + c * 2048 + tid * 8]);
    }
#pragma unroll
    for (int c = 0; c < 2; c++) {
      int r = c * 32 + srow;
      int gch = sch ^ (r & 7);
      gload_lds16(Bb + (size_t)r * K + k0 + gch * 8,
                  &lB[buf * 4096 + c * 2048 + tid * 8]);
    }
  };

  int nt = K >> 6;
  stage(0, 0);
  stage(1, 64);

  int cur = 0;
  for (int t = 0; t < nt; ++t) {
    if (t + 1 < nt) asm volatile("s_waitcnt vmcnt(6)" ::: "memory");
    else            asm volatile("s_waitcnt vmcnt(0)" ::: "memory");
    __builtin_amdgcn_s_barrier();

    int nb = cur + 2; if (nb >= 3) nb -= 3;
    if (t + 2 < nt) stage(nb, (t + 2) << 6);

    bf16x8 af0[4], af1[4], bf0[2], bf1[2];
#pragma unroll
    for (int m = 0; m < 4; m++) {
      int row = wm * 64 + m * 16 + lrow;
      const ushort* p = &lA[cur * 8192 + row * 64];
      af0[m] = *(const bf16x8*)(p + (((lg    ) ^ (row & 7)) << 3));
      af1[m] = *(const bf16x8*)(p + (((lg + 4) ^ (row & 7)) << 3));
    }
#pragma unroll
    for (int n = 0; n < 2; n++) {
      int row = wn * 32 + n * 16 + lrow;
      const ushort* p = &lB[cur * 4096 + row * 64];
      bf0[n] = *(const bf16x8*)(p + (((lg    ) ^ (row & 7)) << 3));
      bf1[n] = *(const bf16x8*)(p + (((lg + 4) ^ (row & 7)) << 3));
    }

    __builtin_amdgcn_s_setprio(1);
#pragma unroll
    for (int m = 0; m < 4; m++)
#pragma unroll
      for (int n = 0; n < 2; n++) {
        acc[m][n] = mfma16(af0[m], bf0[n], acc[m][n]);
        acc[m][n] = mfma16(af1[m], bf1[n], acc[m][n]);
      }
    __builtin_amdgcn_s_setprio(0);

    cur = (cur + 1 == 3) ? 0 : cur + 1;
  }
  __builtin_amdgcn_s_barrier();   // all waves done with MFMA before LDS reuse

  // ---------------- epilogue: acc -> LDS f32 tile -> rope/reshape ----------
  float* lt = (float*)smem;                    // [128][68]
#pragma unroll
  for (int m = 0; m < 4; m++) {
    int row = wm * 64 + m * 16 + lg * 4;
#pragma unroll
    for (int n = 0; n < 2; n++) {
      int col = wn * 32 + n * 16 + lrow;
#pragma unroll
      for (int r = 0; r < 4; r++)
        lt[(row + r) * 68 + col] = acc[m][n][r];
    }
  }
  __syncthreads();

  int t0 = bm * 128;
  int b = t0 >> 11;
  int tloc = t0 & 2047;

  if (bn < 32) {
    bool isQ = (bn < 16);
    int h = bn & 15;
    const float QS = 0.125f * 1.44269504088896340736f;
    float sc = isQ ? QS : 1.0f;
    ushort* dst = (isQ ? Qo : Ko) + ((size_t)(b * NHEAD + h) * TSEQ) * HDIM;
    int row = tid >> 1, f0 = (tid & 1) * 16;
    int t = tloc + row;
    ushort lo[16], hi[16];
#pragma unroll
    for (int j = 0; j < 16; j++) {
      int f = f0 + j;
      float2 cs = tab[t * 32 + f];
      float x1 = lt[row * 68 + f], x2 = lt[row * 68 + f + 32];
      lo[j] = f2bf((x1 * cs.x - x2 * cs.y) * sc);
      hi[j] = f2bf((x1 * cs.y + x2 * cs.x) * sc);
    }
    ushort* dr = dst + (size_t)t * HDIM;
#pragma unroll
    for (int c = 0; c < 4; c++) {
      *(ushort4*)&dr[f0 + c * 4]      = *(ushort4*)&lo[c * 4];
      *(ushort4*)&dr[32 + f0 + c * 4] = *(ushort4*)&hi[c * 4];
    }
  } else {
    int h = bn - 32;
    ushort* dst = VTo + (size_t)(b * NHEAD + h) * HDIM * TSEQ;
    int f = tid >> 2, tc0 = (tid & 3) * 32;
    ushort buf[32];
#pragma unroll
    for (int j = 0; j < 32; j++)
      buf[j] = f2bf(lt[(tc0 + j) * 68 + f]);
    ushort* dr = dst + (size_t)f * TSEQ + tloc + tc0;
#pragma unroll
    for (int c = 0; c < 8; c++)
      *(ushort4*)&dr[c * 4] = *(ushort4*)&buf[c * 4];
  }
}

// ---------------- attention (flash, causal, 4-wave, PAIRED q-tiles) --------
// Q arrives pre-scaled by 0.125*log2e from qkv_gemm.
__global__ __launch_bounds__(256, 4)
void attn_kernel(const ushort* __restrict__ Q, const ushort* __restrict__ Kd,
                 const ushort* __restrict__ VT, ushort* __restrict__ O) {
  int bh = blockIdx.x;
  int p = blockIdx.y;               // 0..15
  int tid = threadIdx.x;
  int lane = tid & 63, w = tid >> 6;
  int lr = lane & 15, lg = lane >> 4;

  const ushort* Qb = Q + (size_t)bh * TSEQ * HDIM;
  const ushort* Kb = Kd + (size_t)bh * TSEQ * HDIM;
  const ushort* Vb = VT + (size_t)bh * HDIM * TSEQ;

  __shared__ ushort lK[2][64 * 64];
  __shared__ ushort lV[2][64 * 64];
  __shared__ ushort pt[4][16 * 64];
  ushort* myp = pt[w];

  int srow0 = tid >> 3, sch = tid & 7;

  auto stage = [&](int buf, int kt) {
#pragma unroll
    for (int c = 0; c < 2; c++) {
      int r = c * 32 + srow0;
      int gch = sch ^ (r & 7);
      gload_lds16(Kb + (size_t)(kt + r) * HDIM + gch * 8,
                  &lK[buf][c * 2048 + tid * 8]);
      gload_lds16(Vb + (size_t)r * TSEQ + kt + gch * 8,
                  &lV[buf][c * 2048 + tid * 8]);
    }
  };

  int b = bh >> 4, h = bh & 15;

  for (int half = 0; half < 2; half++) {
    int qb = half == 0 ? (31 - p) : p;
    int nt = qb + 1;                  // 64-key tiles
    int qw = qb * 64 + w * 16;
    int q_abs = qw + lr;

    bf16x8 aq0 = *(const bf16x8*)&Qb[(size_t)q_abs * HDIM + lg * 8];
    bf16x8 aq1 = *(const bf16x8*)&Qb[(size_t)q_abs * HDIM + 32 + lg * 8];

    float m_run = -1e30f, l_run = 0.0f;
    f32x4 o[4] = {};

    stage(0, 0);
    __syncthreads();

    for (int it = 0; it < nt; ++it) {
      int kt = it * 64;
      int buf = it & 1;
      bool diag = (it == nt - 1);

      if (it + 1 < nt) stage(buf ^ 1, kt + 64);

      f32x4 sa[4];
#pragma unroll
      for (int cb = 0; cb < 4; cb++) {
        int row = cb * 16 + lr;
        const ushort* kp = &lK[buf][row * 64];
        bf16x8 k0 = *(const bf16x8*)(kp + (((lg    ) ^ (row & 7)) << 3));
        bf16x8 k1 = *(const bf16x8*)(kp + (((lg + 4) ^ (row & 7)) << 3));
        f32x4 z = {};
        z = mfma16(k0, aq0, z);
        sa[cb] = mfma16(k1, aq1, z);
      }

      if (diag) {
#pragma unroll
        for (int cb = 0; cb < 4; cb++)
#pragma unroll
          for (int r = 0; r < 4; r++)
            if (kt + cb * 16 + lg * 4 + r > q_abs) sa[cb][r] = -1e30f;
      }

      f32x4 m4;
#pragma unroll
      for (int r = 0; r < 4; r++)
        m4[r] = fmaxf(fmaxf(sa[0][r], sa[1][r]), fmaxf(sa[2][r], sa[3][r]));
      float mx = fmaxf(fmaxf(m4[0], m4[1]), fmaxf(m4[2], m4[3]));
      mx = fmaxf(mx, __shfl_xor(mx, 16, 64));
      mx = fmaxf(mx, __shfl_xor(mx, 32, 64));
      float mn = fmaxf(m_run, mx);
      float rescale = __builtin_amdgcn_exp2f(m_run - mn);
      m_run = mn;

      float ps = 0.0f;
      uint2 pk[4];
#pragma unroll
      for (int cb = 0; cb < 4; cb++) {
        float p0 = __builtin_amdgcn_exp2f(sa[cb][0] - mn);
        float p1 = __builtin_amdgcn_exp2f(sa[cb][1] - mn);
        float p2 = __builtin_amdgcn_exp2f(sa[cb][2] - mn);
        float p3 = __builtin_amdgcn_exp2f(sa[cb][3] - mn);
        ps += (p0 + p1) + (p2 + p3);
        pk[cb].x = cvt_pk_bf16(p0, p1);
        pk[cb].y = cvt_pk_bf16(p2, p3);
      }
      ps += __shfl_xor(ps, 16, 64);
      ps += __shfl_xor(ps, 32, 64);
      l_run = l_run * rescale + ps;

#pragma unroll
      for (int cb = 0; cb < 4; cb++)
        *(uint2*)&myp[lr * 64 + (((cb * 4 + lg) ^ lr) << 2)] = pk[cb];

#pragma unroll
      for (int d = 0; d < 4; d++)
#pragma unroll
        for (int r = 0; r < 4; r++) o[d][r] *= rescale;

      union U8 { uint2 h[2]; bf16x8 v; };
      U8 t0, t1;
      t0.h[0] = *(const uint2*)&myp[lr * 64 + (((lg * 2    ) ^ lr) << 2)];
      t0.h[1] = *(const uint2*)&myp[lr * 64 + (((lg * 2 + 1) ^ lr) << 2)];
      t1.h[0] = *(const uint2*)&myp[lr * 64 + (((8 + lg * 2    ) ^ lr) << 2)];
      t1.h[1] = *(const uint2*)&myp[lr * 64 + (((8 + lg * 2 + 1) ^ lr) << 2)];

#pragma unroll
      for (int d = 0; d < 4; d++) {
        int row = d * 16 + lr;
        const ushort* vp = &lV[buf][row * 64];
        bf16x8 va0 = *(const bf16x8*)(vp + (((lg    ) ^ (row & 7)) << 3));
        bf16x8 va1 = *(const bf16x8*)(vp + (((lg + 4) ^ (row & 7)) << 3));
        o[d] = mfma16(va0, t0.v, o[d]);
        o[d] = mfma16(va1, t1.v, o[d]);
      }

      __syncthreads();
    }

    float linv = 1.0f / l_run;
    size_t obase = (size_t)(b * TSEQ + qw + lr) * DMODEL + h * 64;
#pragma unroll
    for (int d = 0; d < 4; d++) {
      uint2 st;
      st.x = cvt_pk_bf16(o[d][0] * linv, o[d][1] * linv);
      st.y = cvt_pk_bf16(o[d][2] * linv, o[d][3] * linv);
      *(uint2*)&O[obase + d * 16 + lg * 4] = st;
    }
  }
}

// ---------------- GEMM 128x64 ring-3 counted-vmcnt (T3+T4 at 128-tile) -----
// EPI: 1 +resid f32; 2 +bias,gelu bf16; 3 +bias+resid f32.
template <int EPI>
__global__ __launch_bounds__(256)
void gemm_kernel(const ushort* __restrict__ A, const ushort* __restrict__ Bt,
                 void* __restrict__ Cout, const float* __restrict__ bias,
                 const float* __restrict__ resid, int M, int N, int K,
                 int nbn) {
  extern __shared__ ushort smem[];
  ushort* lA = smem;             // [3][8192]
  ushort* lB = smem + 24576;     // [3][4096]
  int tid = threadIdx.x;
  int lane = tid & 63, w = tid >> 6;
  int wm = w >> 1, wn = w & 1;

  int nwg = gridDim.x;
  int cpx = nwg >> 3;
  int wg = ((int)blockIdx.x & 7) * cpx + ((int)blockIdx.x >> 3);
  int bm = wg / nbn, bn = wg % nbn;

  f32x4 acc[4][2] = {};

  const ushort* Ab = A + (size_t)bm * 128 * K;
  const ushort* Bb = Bt + (size_t)bn * 64 * K;
  int lrow = lane & 15, lg = lane >> 4;
  int srow = tid >> 3, sch = tid & 7;

  auto stage = [&](int buf, int k0) {
#pragma unroll
    for (int c = 0; c < 4; c++) {
      int r = c * 32 + srow;
      int gch = sch ^ (r & 7);
      gload_lds16(Ab + (size_t)r * K + k0 + gch * 8,
                  &lA[buf * 8192 + c * 2048 + tid * 8]);
    }
#pragma unroll
    for (int c = 0; c < 2; c++) {
      int r = c * 32 + srow;
      int gch = sch ^ (r & 7);
      gload_lds16(Bb + (size_t)r * K + k0 + gch * 8,
                  &lB[buf * 4096 + c * 2048 + tid * 8]);
    }
  };

  int nt = K >> 6;
  stage(0, 0);
  stage(1, 64);

  int cur = 0;
  for (int t = 0; t < nt; ++t) {
    // counted fence: tile t's 6 loads were issued 2 iterations ago.
    if (t + 1 < nt) asm volatile("s_waitcnt vmcnt(6)" ::: "memory");
    else            asm volatile("s_waitcnt vmcnt(0)" ::: "memory");
    __builtin_amdgcn_s_barrier();

    int nb = cur + 2; if (nb >= 3) nb -= 3;
    if (t + 2 < nt) stage(nb, (t + 2) << 6);

    bf16x8 af0[4], af1[4], bf0[2], bf1[2];
#pragma unroll
    for (int m = 0; m < 4; m++) {
      int row = wm * 64 + m * 16 + lrow;
      const ushort* p = &lA[cur * 8192 + row * 64];
      af0[m] = *(const bf16x8*)(p + (((lg    ) ^ (row & 7)) << 3));
      af1[m] = *(const bf16x8*)(p + (((lg + 4) ^ (row & 7)) << 3));
    }
#pragma unroll
    for (int n = 0; n < 2; n++) {
      int row = wn * 32 + n * 16 + lrow;
      const ushort* p = &lB[cur * 4096 + row * 64];
      bf0[n] = *(const bf16x8*)(p + (((lg    ) ^ (row & 7)) << 3));
      bf1[n] = *(const bf16x8*)(p + (((lg + 4) ^ (row & 7)) << 3));
    }

    __builtin_amdgcn_s_setprio(1);
#pragma unroll
    for (int m = 0; m < 4; m++)
#pragma unroll
      for (int n = 0; n < 2; n++) {
        acc[m][n] = mfma16(af0[m], bf0[n], acc[m][n]);
        acc[m][n] = mfma16(af1[m], bf1[n], acc[m][n]);
      }
    __builtin_amdgcn_s_setprio(0);

    cur = (cur + 1 == 3) ? 0 : cur + 1;
  }

#pragma unroll
  for (int m = 0; m < 4; m++) {
    int rbase = bm * 128 + wm * 64 + m * 16 + (lane >> 4) * 4;
#pragma unroll
    for (int n = 0; n < 2; n++) {
      int c = bn * 64 + wn * 32 + n * 16 + (lane & 15);
#pragma unroll
      for (int r = 0; r < 4; r++) {
        float v = acc[m][n][r];
        size_t idx = (size_t)(rbase + r) * N + c;
        if constexpr (EPI == 1) {
          ((float*)Cout)[idx] = v + resid[idx];
        } else if constexpr (EPI == 2) {
          ((ushort*)Cout)[idx] = f2bf(gelu_f(v + bias[c]));
        } else {
          ((float*)Cout)[idx] = v + bias[c] + resid[idx];
        }
      }
    }
  }
}

// ---------------------------------------------------------------------------
extern "C" void kernel_launch(void* const* d_in, const int* in_sizes, int n_in,
                              void* d_out, int out_size, void* d_ws,
                              size_t ws_size, hipStream_t stream) {
  const float* x      = (const float*)d_in[0];
  const int* positions = (const int*)d_in[1];
  const float* ln1_s  = (const float*)d_in[3];
  const float* ln1_b  = (const float*)d_in[4];
  const float* w_qkv  = (const float*)d_in[5];
  const float* w_o    = (const float*)d_in[6];
  const float* ln2_s  = (const float*)d_in[7];
  const float* ln2_b  = (const float*)d_in[8];
  const float* w1     = (const float*)d_in[9];
  const float* b1     = (const float*)d_in[10];
  const float* w2     = (const float*)d_in[11];
  const float* b2     = (const float*)d_in[12];
  float* out = (float*)d_out;

  char* ws = (char*)d_ws;
  size_t off = 0;
  auto nxt = [&](size_t bytes) {
    char* p = ws + off;
    off += (bytes + 255) & ~(size_t)255;
    return p;
  };
  ushort* wqkvT = (ushort*)nxt(3072ULL * 1024 * 2);
  ushort* woT   = (ushort*)nxt(1024ULL * 1024 * 2);
  ushort* w1T   = (ushort*)nxt(4096ULL * 1024 * 2);
  ushort* w2T   = (ushort*)nxt(1024ULL * 4096 * 2);
  ushort* h1    = (ushort*)nxt((size_t)M_ROWS * DMODEL * 2);
  ushort* Qb    = (ushort*)nxt(2ULL * NHEAD * TSEQ * HDIM * 2);
  ushort* Kb    = (ushort*)nxt(2ULL * NHEAD * TSEQ * HDIM * 2);
  ushort* VTb   = (ushort*)nxt(2ULL * NHEAD * TSEQ * HDIM * 2);
  ushort* attn  = (ushort*)nxt((size_t)M_ROWS * DMODEL * 2);
  float*  x2    = (float*)nxt((size_t)M_ROWS * DMODEL * 4);
  ushort* h2    = (ushort*)nxt((size_t)M_ROWS * DMODEL * 2);
  ushort* mid   = (ushort*)nxt((size_t)M_ROWS * 4096 * 2);
  float2* tab   = (float2*)nxt((size_t)TSEQ * 32 * 8);

  // 72 KiB dynamic LDS for the ring-3 GEMMs
  (void)hipFuncSetAttribute((const void*)qkv_gemm,
                            hipFuncAttributeMaxDynamicSharedMemorySize, 73728);
  (void)hipFuncSetAttribute((const void*)gemm_kernel<1>,
                            hipFuncAttributeMaxDynamicSharedMemorySize, 73728);
  (void)hipFuncSetAttribute((const void*)gemm_kernel<2>,
                            hipFuncAttributeMaxDynamicSharedMemorySize, 73728);
  (void)hipFuncSetAttribute((const void*)gemm_kernel<3>,
                            hipFuncAttributeMaxDynamicSharedMemorySize, 73728);

  transpose_all<<<12288, 256, 0, stream>>>(w_qkv, w_o, w1, w2,
                                           wqkvT, woT, w1T, w2T);
  rope_table<<<(TSEQ * 32) / 256, 256, 0, stream>>>(positions, tab);
  ln_kernel<<<M_ROWS, 256, 0, stream>>>(x, ln1_s, ln1_b, h1);
  // fused qkv GEMM + RoPE + reshape: 1536 wgs (BN=64, one head per block)
  qkv_gemm<<<1536, 256, 73728, stream>>>(h1, wqkvT, tab, Qb, Kb, VTb, 1024, 48);
  // attention: paired q-tiles, 512 blocks, uniform 33 k-tiles per block
  attn_kernel<<<dim3(32, 16), 256, 0, stream>>>(Qb, Kb, VTb, attn);
  // wo: M=4096 N=1024 K=1024, 128x64 tiles -> 512 wgs
  gemm_kernel<1><<<512, 256, 73728, stream>>>(attn, woT, x2, nullptr, x, 4096, 1024, 1024, 16);
  ln_kernel<<<M_ROWS, 256, 0, stream>>>(x2, ln2_s, ln2_b, h2);
  // ffn1: M=4096 N=4096 K=1024, 128x64 tiles -> 2048 wgs
  gemm_kernel<2><<<2048, 256, 73728, stream>>>(h2, w1T, mid, b1, nullptr, 4096, 4096, 1024, 64);
  // ffn2: M=4096 N=1024 K=4096, 128x64 tiles -> 512 wgs
  gemm_kernel<3><<<512, 256, 73728, stream>>>(mid, w2T, out, b2, x2, 4096, 1024, 4096, 16);
}

// Round 19
// 224.590 us; speedup vs baseline: 1.0213x; 1.0213x over previous
//
#include <hip/hip_runtime.h>

// Decoder block: B=2 T=2048 D=1024 H=16 hd=64 HIDDEN=4096. All f32 in/out,
// bf16 MFMA internally (threshold is bf16-floor).

typedef __bf16 bf16_t;
typedef bf16_t bf16x8 __attribute__((ext_vector_type(8)));
typedef float f32x4 __attribute__((ext_vector_type(4)));

#define M_ROWS 4096   // B*T
#define DMODEL 1024
#define TSEQ   2048
#define NHEAD  16
#define HDIM   64

__device__ __forceinline__ ushort f2bf(float f) {
  union { float f; unsigned u; } v; v.f = f;
  unsigned r = (v.u + 0x7fffu + ((v.u >> 16) & 1u)) >> 16;
  return (ushort)r;
}
__device__ __forceinline__ float bf2f(ushort u) {
  union { unsigned u; float f; } v; v.u = ((unsigned)u) << 16;
  return v.f;
}
__device__ __forceinline__ unsigned cvt_pk_bf16(float a, float b) {
  unsigned r;
  asm("v_cvt_pk_bf16_f32 %0, %1, %2" : "=v"(r) : "v"(a), "v"(b));
  return r;
}
__device__ __forceinline__ void gload_lds16(const void* g, void* l) {
  __builtin_amdgcn_global_load_lds(
      (const __attribute__((address_space(1))) unsigned*)g,
      (__attribute__((address_space(3))) unsigned*)l, 16, 0, 0);
}
__device__ __forceinline__ f32x4 mfma16(bf16x8 a, bf16x8 b, f32x4 c) {
  return __builtin_amdgcn_mfma_f32_16x16x32_bf16(a, b, c, 0, 0, 0);
}
__device__ __forceinline__ float gelu_f(float x) {
  float y = 0.7978845608028654f * (x + 0.044715f * x * x * x);
  float e = __expf(2.0f * y);
  float t = 1.0f - 2.0f / (e + 1.0f);   // tanh(y), overflow-safe
  return 0.5f * x * (1.0f + t);
}

// ---------------- batched weight transpose + f32->bf16 ---------------------
__global__ __launch_bounds__(256)
void transpose_all(const float* __restrict__ wqkv, const float* __restrict__ wo,
                   const float* __restrict__ w1, const float* __restrict__ w2,
                   ushort* __restrict__ dqkv, ushort* __restrict__ dwo,
                   ushort* __restrict__ dw1, ushort* __restrict__ dw2) {
  int id = blockIdx.x;
  const float* src; ushort* dst; int K, N, nx, loc;
  if (id < 3072)      { src = wqkv; dst = dqkv; K = 1024; N = 3072; nx = 96;  loc = id; }
  else if (id < 4096) { src = wo;   dst = dwo;  K = 1024; N = 1024; nx = 32;  loc = id - 3072; }
  else if (id < 8192) { src = w1;   dst = dw1;  K = 1024; N = 4096; nx = 128; loc = id - 4096; }
  else                { src = w2;   dst = dw2;  K = 4096; N = 1024; nx = 32;  loc = id - 8192; }
  int n0 = (loc % nx) * 32, k0 = (loc / nx) * 32;
  __shared__ float t[32][33];
  int tx = threadIdx.x & 31, ty = threadIdx.x >> 5;
#pragma unroll
  for (int i = 0; i < 4; i++) {
    int k = ty + i * 8;
    t[k][tx] = src[(size_t)(k0 + k) * N + n0 + tx];
  }
  __syncthreads();
#pragma unroll
  for (int i = 0; i < 4; i++) {
    int nn = ty + i * 8;
    dst[(size_t)(n0 + nn) * K + k0 + tx] = f2bf(t[tx][nn]);
  }
}

// ---------------- layernorm (f32 in, bf16 out) -----------------------------
__global__ __launch_bounds__(256)
void ln_kernel(const float* __restrict__ x, const float* __restrict__ sc,
               const float* __restrict__ bi, ushort* __restrict__ out) {
  int row = blockIdx.x;
  int tid = threadIdx.x;
  const float4 v = *(const float4*)&x[(size_t)row * DMODEL + tid * 4];
  float s = v.x + v.y + v.z + v.w;
  float s2 = v.x * v.x + v.y * v.y + v.z * v.z + v.w * v.w;
#pragma unroll
  for (int off = 32; off > 0; off >>= 1) {
    s += __shfl_down(s, off);
    s2 += __shfl_down(s2, off);
  }
  __shared__ float red[8];
  int lane = tid & 63, w = tid >> 6;
  if (lane == 0) { red[w * 2] = s; red[w * 2 + 1] = s2; }
  __syncthreads();
  float S = red[0] + red[2] + red[4] + red[6];
  float S2 = red[1] + red[3] + red[5] + red[7];
  float mu = S * (1.0f / DMODEL);
  float var = S2 * (1.0f / DMODEL) - mu * mu;
  float rs = rsqrtf(var + 1e-6f);
  float4 scv = *(const float4*)&sc[tid * 4];
  float4 biv = *(const float4*)&bi[tid * 4];
  ushort4 o;
  o.x = f2bf((v.x - mu) * rs * scv.x + biv.x);
  o.y = f2bf((v.y - mu) * rs * scv.y + biv.y);
  o.z = f2bf((v.z - mu) * rs * scv.z + biv.z);
  o.w = f2bf((v.w - mu) * rs * scv.w + biv.w);
  *(ushort4*)&out[(size_t)row * DMODEL + tid * 4] = o;
}

// ---------------- rope table -----------------------------------------------
__global__ __launch_bounds__(256)
void rope_table(const int* __restrict__ positions, float2* __restrict__ tab) {
  int i = blockIdx.x * 256 + threadIdx.x;  // T*32
  int t = i >> 5, f = i & 31;
  float inv = __expf(-(float)f * (1.0f / 32.0f) * 9.210340371976184f);
  float a = (float)positions[t] * inv;
  tab[i] = make_float2(cosf(a), sinf(a));
}

// ---------------- fused QKV GEMM + RoPE + reshape --------------------------
// BM=128, BN=64 (one head/block), BK=64 2-phase pipeline. Epilogue: acc ->
// LDS f32 tile -> bn<16: Q (RoPE, pre-scaled 0.125*log2e); bn<32: K (RoPE);
// else V^T. No XCD remap (L3-fit data: m160 shows remap costs ~2%).
__global__ __launch_bounds__(256)
void qkv_gemm(const ushort* __restrict__ A, const ushort* __restrict__ Bt,
              const float2* __restrict__ tab, ushort* __restrict__ Qo,
              ushort* __restrict__ Ko, ushort* __restrict__ VTo, int K,
              int nbn) {
  constexpr int NF = 2;
  __shared__ char smem[49152];                 // lA(32K) | lB(16K); reused by epilogue
  ushort* lA = (ushort*)smem;                  // [2][128*64]
  ushort* lB = (ushort*)(smem + 32768);        // [2][64*64]
  int tid = threadIdx.x;
  int lane = tid & 63, w = tid >> 6;
  int wm = w >> 1, wn = w & 1;

  int wg = (int)blockIdx.x;                    // no XCD remap (L3-fit)
  int bm = wg / nbn, bn = wg % nbn;

  f32x4 acc[4][NF] = {};

  const ushort* Ab = A + (size_t)bm * 128 * K;
  const ushort* Bb = Bt + (size_t)bn * 64 * K;
  int lrow = lane & 15, lg = lane >> 4;
  int srow = tid >> 3, sch = tid & 7;

  auto stage = [&](int buf, int k0) {
#pragma unroll
    for (int c = 0; c < 4; c++) {
      int r = c * 32 + srow;
      int gch = sch ^ (r & 7);
      gload_lds16(Ab + (size_t)r * K + k0 + gch * 8,
                  &lA[buf * 8192 + c * 2048 + tid * 8]);
    }
#pragma unroll
    for (int c = 0; c < 2; c++) {
      int r = c * 32 + srow;
      int gch = sch ^ (r & 7);
      gload_lds16(Bb + (size_t)r * K + k0 + gch * 8,
                  &lB[buf * 4096 + c * 2048 + tid * 8]);
    }
  };

  int nt = K >> 6;
  stage(0, 0);
  __syncthreads();

  for (int t = 0; t < nt; ++t) {
    int cur = t & 1;
    bf16x8 af0[4], af1[4], bf0[NF], bf1[NF];
#pragma unroll
    for (int m = 0; m < 4; m++) {
      int row = wm * 64 + m * 16 + lrow;
      const ushort* p = &lA[cur * 8192 + row * 64];
      af0[m] = *(const bf16x8*)(p + (((lg    ) ^ (row & 7)) << 3));
      af1[m] = *(const bf16x8*)(p + (((lg + 4) ^ (row & 7)) << 3));
    }
#pragma unroll
    for (int n = 0; n < NF; n++) {
      int row = wn * 32 + n * 16 + lrow;
      const ushort* p = &lB[cur * 4096 + row * 64];
      bf0[n] = *(const bf16x8*)(p + (((lg    ) ^ (row & 7)) << 3));
      bf1[n] = *(const bf16x8*)(p + (((lg + 4) ^ (row & 7)) << 3));
    }
    if (t + 1 < nt) stage(cur ^ 1, (t + 1) << 6);
    __builtin_amdgcn_s_setprio(1);
#pragma unroll
    for (int m = 0; m < 4; m++)
#pragma unroll
      for (int n = 0; n < NF; n++)
        acc[m][n] = mfma16(af0[m], bf0[n], acc[m][n]);
#pragma unroll
    for (int m = 0; m < 4; m++)
#pragma unroll
      for (int n = 0; n < NF; n++)
        acc[m][n] = mfma16(af1[m], bf1[n], acc[m][n]);
    __builtin_amdgcn_s_setprio(0);
    __builtin_amdgcn_sched_barrier(0);
    asm volatile("s_waitcnt vmcnt(0)" ::: "memory");
    __builtin_amdgcn_s_barrier();
  }

  // ---------------- epilogue: acc -> LDS f32 tile -> rope/reshape ----------
  float* lt = (float*)smem;                    // [128][68]
#pragma unroll
  for (int m = 0; m < 4; m++) {
    int row = wm * 64 + m * 16 + lg * 4;
#pragma unroll
    for (int n = 0; n < NF; n++) {
      int col = wn * 32 + n * 16 + lrow;
#pragma unroll
      for (int r = 0; r < 4; r++)
        lt[(row + r) * 68 + col] = acc[m][n][r];
    }
  }
  __syncthreads();

  int t0 = bm * 128;
  int b = t0 >> 11;
  int tloc = t0 & 2047;

  if (bn < 32) {
    bool isQ = (bn < 16);
    int h = bn & 15;
    const float QS = 0.125f * 1.44269504088896340736f;
    float sc = isQ ? QS : 1.0f;
    ushort* dst = (isQ ? Qo : Ko) + ((size_t)(b * NHEAD + h) * TSEQ) * HDIM;
    int row = tid >> 1, f0 = (tid & 1) * 16;
    int t = tloc + row;
    ushort lo[16], hi[16];
#pragma unroll
    for (int j = 0; j < 16; j++) {
      int f = f0 + j;
      float2 cs = tab[t * 32 + f];
      float x1 = lt[row * 68 + f], x2 = lt[row * 68 + f + 32];
      lo[j] = f2bf((x1 * cs.x - x2 * cs.y) * sc);
      hi[j] = f2bf((x1 * cs.y + x2 * cs.x) * sc);
    }
    ushort* dr = dst + (size_t)t * HDIM;
#pragma unroll
    for (int c = 0; c < 4; c++) {
      *(ushort4*)&dr[f0 + c * 4]      = *(ushort4*)&lo[c * 4];
      *(ushort4*)&dr[32 + f0 + c * 4] = *(ushort4*)&hi[c * 4];
    }
  } else {
    int h = bn - 32;
    ushort* dst = VTo + (size_t)(b * NHEAD + h) * HDIM * TSEQ;
    int f = tid >> 2, tc0 = (tid & 3) * 32;
    ushort buf[32];
#pragma unroll
    for (int j = 0; j < 32; j++)
      buf[j] = f2bf(lt[(tc0 + j) * 68 + f]);
    ushort* dr = dst + (size_t)f * TSEQ + tloc + tc0;
#pragma unroll
    for (int c = 0; c < 8; c++)
      *(ushort4*)&dr[c * 4] = *(ushort4*)&buf[c * 4];
  }
}

// ---------------- attention (flash, causal, 4-wave, PAIRED q-tiles) --------
// Q arrives pre-scaled by 0.125*log2e from qkv_gemm.
__global__ __launch_bounds__(256, 4)
void attn_kernel(const ushort* __restrict__ Q, const ushort* __restrict__ Kd,
                 const ushort* __restrict__ VT, ushort* __restrict__ O) {
  int bh = blockIdx.x;
  int p = blockIdx.y;               // 0..15
  int tid = threadIdx.x;
  int lane = tid & 63, w = tid >> 6;
  int lr = lane & 15, lg = lane >> 4;

  const ushort* Qb = Q + (size_t)bh * TSEQ * HDIM;
  const ushort* Kb = Kd + (size_t)bh * TSEQ * HDIM;
  const ushort* Vb = VT + (size_t)bh * HDIM * TSEQ;

  __shared__ ushort lK[2][64 * 64];
  __shared__ ushort lV[2][64 * 64];
  __shared__ ushort pt[4][16 * 64];
  ushort* myp = pt[w];

  int srow0 = tid >> 3, sch = tid & 7;

  auto stage = [&](int buf, int kt) {
#pragma unroll
    for (int c = 0; c < 2; c++) {
      int r = c * 32 + srow0;
      int gch = sch ^ (r & 7);
      gload_lds16(Kb + (size_t)(kt + r) * HDIM + gch * 8,
                  &lK[buf][c * 2048 + tid * 8]);
      gload_lds16(Vb + (size_t)r * TSEQ + kt + gch * 8,
                  &lV[buf][c * 2048 + tid * 8]);
    }
  };

  int b = bh >> 4, h = bh & 15;

  for (int half = 0; half < 2; half++) {
    int qb = half == 0 ? (31 - p) : p;
    int nt = qb + 1;                  // 64-key tiles
    int qw = qb * 64 + w * 16;
    int q_abs = qw + lr;

    bf16x8 aq0 = *(const bf16x8*)&Qb[(size_t)q_abs * HDIM + lg * 8];
    bf16x8 aq1 = *(const bf16x8*)&Qb[(size_t)q_abs * HDIM + 32 + lg * 8];

    float m_run = -1e30f, l_run = 0.0f;
    f32x4 o[4] = {};

    stage(0, 0);
    __syncthreads();

    for (int it = 0; it < nt; ++it) {
      int kt = it * 64;
      int buf = it & 1;
      bool diag = (it == nt - 1);

      if (it + 1 < nt) stage(buf ^ 1, kt + 64);

      f32x4 sa[4];
#pragma unroll
      for (int cb = 0; cb < 4; cb++) {
        int row = cb * 16 + lr;
        const ushort* kp = &lK[buf][row * 64];
        bf16x8 k0 = *(const bf16x8*)(kp + (((lg    ) ^ (row & 7)) << 3));
        bf16x8 k1 = *(const bf16x8*)(kp + (((lg + 4) ^ (row & 7)) << 3));
        f32x4 z = {};
        z = mfma16(k0, aq0, z);
        sa[cb] = mfma16(k1, aq1, z);
      }

      if (diag) {
#pragma unroll
        for (int cb = 0; cb < 4; cb++)
#pragma unroll
          for (int r = 0; r < 4; r++)
            if (kt + cb * 16 + lg * 4 + r > q_abs) sa[cb][r] = -1e30f;
      }

      f32x4 m4;
#pragma unroll
      for (int r = 0; r < 4; r++)
        m4[r] = fmaxf(fmaxf(sa[0][r], sa[1][r]), fmaxf(sa[2][r], sa[3][r]));
      float mx = fmaxf(fmaxf(m4[0], m4[1]), fmaxf(m4[2], m4[3]));
      mx = fmaxf(mx, __shfl_xor(mx, 16, 64));
      mx = fmaxf(mx, __shfl_xor(mx, 32, 64));
      float mn = fmaxf(m_run, mx);
      float rescale = __builtin_amdgcn_exp2f(m_run - mn);
      m_run = mn;

      float ps = 0.0f;
      uint2 pk[4];
#pragma unroll
      for (int cb = 0; cb < 4; cb++) {
        float p0 = __builtin_amdgcn_exp2f(sa[cb][0] - mn);
        float p1 = __builtin_amdgcn_exp2f(sa[cb][1] - mn);
        float p2 = __builtin_amdgcn_exp2f(sa[cb][2] - mn);
        float p3 = __builtin_amdgcn_exp2f(sa[cb][3] - mn);
        ps += (p0 + p1) + (p2 + p3);
        pk[cb].x = cvt_pk_bf16(p0, p1);
        pk[cb].y = cvt_pk_bf16(p2, p3);
      }
      ps += __shfl_xor(ps, 16, 64);
      ps += __shfl_xor(ps, 32, 64);
      l_run = l_run * rescale + ps;

#pragma unroll
      for (int cb = 0; cb < 4; cb++)
        *(uint2*)&myp[lr * 64 + (((cb * 4 + lg) ^ lr) << 2)] = pk[cb];

#pragma unroll
      for (int d = 0; d < 4; d++)
#pragma unroll
        for (int r = 0; r < 4; r++) o[d][r] *= rescale;

      union U8 { uint2 h[2]; bf16x8 v; };
      U8 t0, t1;
      t0.h[0] = *(const uint2*)&myp[lr * 64 + (((lg * 2    ) ^ lr) << 2)];
      t0.h[1] = *(const uint2*)&myp[lr * 64 + (((lg * 2 + 1) ^ lr) << 2)];
      t1.h[0] = *(const uint2*)&myp[lr * 64 + (((8 + lg * 2    ) ^ lr) << 2)];
      t1.h[1] = *(const uint2*)&myp[lr * 64 + (((8 + lg * 2 + 1) ^ lr) << 2)];

#pragma unroll
      for (int d = 0; d < 4; d++) {
        int row = d * 16 + lr;
        const ushort* vp = &lV[buf][row * 64];
        bf16x8 va0 = *(const bf16x8*)(vp + (((lg    ) ^ (row & 7)) << 3));
        bf16x8 va1 = *(const bf16x8*)(vp + (((lg + 4) ^ (row & 7)) << 3));
        o[d] = mfma16(va0, t0.v, o[d]);
        o[d] = mfma16(va1, t1.v, o[d]);
      }

      __syncthreads();
    }

    float linv = 1.0f / l_run;
    size_t obase = (size_t)(b * TSEQ + qw + lr) * DMODEL + h * 64;
#pragma unroll
    for (int d = 0; d < 4; d++) {
      uint2 st;
      st.x = cvt_pk_bf16(o[d][0] * linv, o[d][1] * linv);
      st.y = cvt_pk_bf16(o[d][2] * linv, o[d][3] * linv);
      *(uint2*)&O[obase + d * 16 + lg * 4] = st;
    }
  }
}

// ---------------- GEMM 128xBN 2-phase (r7-measured best structure) ---------
// No XCD remap (L3-fit data). bn-fastest for A-panel L2 reuse.
template <int EPI, int BN>
__global__ __launch_bounds__(256)
void gemm_kernel(const ushort* __restrict__ A, const ushort* __restrict__ Bt,
                 void* __restrict__ Cout, const float* __restrict__ bias,
                 const float* __restrict__ resid, int M, int N, int K,
                 int nbn) {
  constexpr int NF = BN / 32;
  __shared__ ushort lA[2][128 * 64];
  __shared__ ushort lB[2][BN * 64];
  int tid = threadIdx.x;
  int lane = tid & 63, w = tid >> 6;
  int wm = w >> 1, wn = w & 1;

  int wg = (int)blockIdx.x;                    // no XCD remap (L3-fit)
  int bm = wg / nbn, bn = wg % nbn;

  f32x4 acc[4][NF] = {};

  const ushort* Ab = A + (size_t)bm * 128 * K;
  const ushort* Bb = Bt + (size_t)bn * BN * K;
  int lrow = lane & 15, lg = lane >> 4;
  int srow = tid >> 3, sch = tid & 7;

  auto stage = [&](int buf, int k0) {
#pragma unroll
    for (int c = 0; c < 4; c++) {
      int r = c * 32 + srow;
      int gch = sch ^ (r & 7);
      gload_lds16(Ab + (size_t)r * K + k0 + gch * 8,
                  &lA[buf][c * 2048 + tid * 8]);
    }
#pragma unroll
    for (int c = 0; c < NF; c++) {
      int r = c * 32 + srow;
      int gch = sch ^ (r & 7);
      gload_lds16(Bb + (size_t)r * K + k0 + gch * 8,
                  &lB[buf][c * 2048 + tid * 8]);
    }
  };

  int nt = K >> 6;
  stage(0, 0);
  __syncthreads();

  for (int t = 0; t < nt; ++t) {
    int cur = t & 1;

    bf16x8 af0[4], af1[4], bf0[NF], bf1[NF];
#pragma unroll
    for (int m = 0; m < 4; m++) {
      int row = wm * 64 + m * 16 + lrow;
      const ushort* p = &lA[cur][row * 64];
      af0[m] = *(const bf16x8*)(p + (((lg    ) ^ (row & 7)) << 3));
      af1[m] = *(const bf16x8*)(p + (((lg + 4) ^ (row & 7)) << 3));
    }
#pragma unroll
    for (int n = 0; n < NF; n++) {
      int row = wn * (BN / 2) + n * 16 + lrow;
      const ushort* p = &lB[cur][row * 64];
      bf0[n] = *(const bf16x8*)(p + (((lg    ) ^ (row & 7)) << 3));
      bf1[n] = *(const bf16x8*)(p + (((lg + 4) ^ (row & 7)) << 3));
    }

    if (t + 1 < nt) stage(cur ^ 1, (t + 1) << 6);

    __builtin_amdgcn_s_setprio(1);
#pragma unroll
    for (int m = 0; m < 4; m++)
#pragma unroll
      for (int n = 0; n < NF; n++)
        acc[m][n] = mfma16(af0[m], bf0[n], acc[m][n]);
#pragma unroll
    for (int m = 0; m < 4; m++)
#pragma unroll
      for (int n = 0; n < NF; n++)
        acc[m][n] = mfma16(af1[m], bf1[n], acc[m][n]);
    __builtin_amdgcn_s_setprio(0);

    __builtin_amdgcn_sched_barrier(0);
    asm volatile("s_waitcnt vmcnt(0)" ::: "memory");
    __builtin_amdgcn_s_barrier();
  }

#pragma unroll
  for (int m = 0; m < 4; m++) {
    int rbase = bm * 128 + wm * 64 + m * 16 + (lane >> 4) * 4;
#pragma unroll
    for (int n = 0; n < NF; n++) {
      int c = bn * BN + wn * (BN / 2) + n * 16 + (lane & 15);
#pragma unroll
      for (int r = 0; r < 4; r++) {
        float v = acc[m][n][r];
        size_t idx = (size_t)(rbase + r) * N + c;
        if constexpr (EPI == 0) {
          ((ushort*)Cout)[idx] = f2bf(v);
        } else if constexpr (EPI == 1) {
          ((float*)Cout)[idx] = v + resid[idx];
        } else if constexpr (EPI == 2) {
          ((ushort*)Cout)[idx] = f2bf(gelu_f(v + bias[c]));
        } else {
          ((float*)Cout)[idx] = v + bias[c] + resid[idx];
        }
      }
    }
  }
}

// ---------------------------------------------------------------------------
extern "C" void kernel_launch(void* const* d_in, const int* in_sizes, int n_in,
                              void* d_out, int out_size, void* d_ws,
                              size_t ws_size, hipStream_t stream) {
  const float* x      = (const float*)d_in[0];
  const int* positions = (const int*)d_in[1];
  const float* ln1_s  = (const float*)d_in[3];
  const float* ln1_b  = (const float*)d_in[4];
  const float* w_qkv  = (const float*)d_in[5];
  const float* w_o    = (const float*)d_in[6];
  const float* ln2_s  = (const float*)d_in[7];
  const float* ln2_b  = (const float*)d_in[8];
  const float* w1     = (const float*)d_in[9];
  const float* b1     = (const float*)d_in[10];
  const float* w2     = (const float*)d_in[11];
  const float* b2     = (const float*)d_in[12];
  float* out = (float*)d_out;

  char* ws = (char*)d_ws;
  size_t off = 0;
  auto nxt = [&](size_t bytes) {
    char* p = ws + off;
    off += (bytes + 255) & ~(size_t)255;
    return p;
  };
  ushort* wqkvT = (ushort*)nxt(3072ULL * 1024 * 2);
  ushort* woT   = (ushort*)nxt(1024ULL * 1024 * 2);
  ushort* w1T   = (ushort*)nxt(4096ULL * 1024 * 2);
  ushort* w2T   = (ushort*)nxt(1024ULL * 4096 * 2);
  ushort* h1    = (ushort*)nxt((size_t)M_ROWS * DMODEL * 2);
  ushort* Qb    = (ushort*)nxt(2ULL * NHEAD * TSEQ * HDIM * 2);
  ushort* Kb    = (ushort*)nxt(2ULL * NHEAD * TSEQ * HDIM * 2);
  ushort* VTb   = (ushort*)nxt(2ULL * NHEAD * TSEQ * HDIM * 2);
  ushort* attn  = (ushort*)nxt((size_t)M_ROWS * DMODEL * 2);
  float*  x2    = (float*)nxt((size_t)M_ROWS * DMODEL * 4);
  ushort* h2    = (ushort*)nxt((size_t)M_ROWS * DMODEL * 2);
  ushort* mid   = (ushort*)nxt((size_t)M_ROWS * 4096 * 2);
  float2* tab   = (float2*)nxt((size_t)TSEQ * 32 * 8);

  transpose_all<<<12288, 256, 0, stream>>>(w_qkv, w_o, w1, w2,
                                           wqkvT, woT, w1T, w2T);
  rope_table<<<(TSEQ * 32) / 256, 256, 0, stream>>>(positions, tab);
  ln_kernel<<<M_ROWS, 256, 0, stream>>>(x, ln1_s, ln1_b, h1);
  // fused qkv GEMM + RoPE + reshape: 1536 wgs (BN=64, one head per block)
  qkv_gemm<<<1536, 256, 0, stream>>>(h1, wqkvT, tab, Qb, Kb, VTb, 1024, 48);
  // attention: paired q-tiles, 512 blocks, uniform 33 k-tiles per block
  attn_kernel<<<dim3(32, 16), 256, 0, stream>>>(Qb, Kb, VTb, attn);
  // wo: M=4096 N=1024 K=1024, 128x64 tiles -> 512 wgs
  gemm_kernel<1, 64><<<512, 256, 0, stream>>>(attn, woT, x2, nullptr, x, 4096, 1024, 1024, 16);
  ln_kernel<<<M_ROWS, 256, 0, stream>>>(x2, ln2_s, ln2_b, h2);
  // ffn1: M=4096 N=4096 K=1024, 128x128 tiles -> 1024 wgs
  gemm_kernel<2, 128><<<1024, 256, 0, stream>>>(h2, w1T, mid, b1, nullptr, 4096, 4096, 1024, 32);
  // ffn2: M=4096 N=1024 K=4096, 128x64 tiles -> 512 wgs
  gemm_kernel<3, 64><<<512, 256, 0, stream>>>(mid, w2T, out, b2, x2, 4096, 1024, 4096, 16);
}